// Round 4
// baseline (342.586 us; speedup 1.0000x reference)
//
#include <hip/hip_runtime.h>
#include <stdint.h>

// Problem constants (CorrelationModule): x[8,384,48,48], O=512, N=48*48=2304
#define B_    8
#define CIN   384
#define OCH   512
#define NTOK  2304
#define SCALE 0.044194173824159216f  // 1/sqrt(512)

typedef unsigned short u16;
typedef u16   u16x8 __attribute__((ext_vector_type(8)));
typedef short s16x8 __attribute__((ext_vector_type(8)));
typedef float f32x4 __attribute__((ext_vector_type(4)));

// ---------- bf16 helpers (bit-level, RNE) ----------
__device__ __forceinline__ u16 f2bf(float f) {
    union { uint32_t i; float f; } v; v.f = f;
    uint32_t r = v.i + 0x7fffu + ((v.i >> 16) & 1u);
    return (u16)(r >> 16);
}

// ---------- async global->LDS (width 16) ----------
typedef __attribute__((address_space(1))) const uint32_t glb_u32;
typedef __attribute__((address_space(3))) uint32_t lds_u32;

__device__ __forceinline__ void gld16(const u16* g, u16* l) {
    __builtin_amdgcn_global_load_lds((glb_u32*)g, (lds_u32*)l, 16, 0, 0);
}

// =====================================================================
// BRICK FORMAT for all bf16 intermediates.
// brick (g, c) = rows g*16..+16, cols c*32..+32, 512 u16, chunk l (16 B)
// = (col8 = l>>4, row = l&15).  u16 offset of (row, col) inside brick:
//   ((col>>3)&3)*128 + (row&15)*8 + (col&7)
// =====================================================================
__device__ __forceinline__ size_t baddr(int row, int col, int Kc) {
    return ((size_t)(row >> 4) * (Kc >> 5) + (col >> 5)) * 512
         + (size_t)(((col >> 3) & 3) * 128 + (row & 15) * 8 + (col & 7));
}

// =====================================================================
// R11: 256-row tile, counted-vmcnt, 3-buffer 2-deep pipeline (T3+T4).
// R0/R9/R10 all drained vmcnt to 0 every K-step (__syncthreads forces
// the compiler's vmcnt(0); m218: drain-0 == no pipeline).  Here:
//  - raw s_barrier (no compiler drain) + asm "memory" fences
//  - iteration kt: wait OWN vmcnt(L) -> own tile-kt loads done; barrier
//    joins all waves -> buffer kt%3 fully valid.  Stage tile kt+2 into
//    buffer (kt+2)%3 == (kt-1)%3 AFTER the barrier: all waves already
//    finished reading it at iteration kt-1 (they passed this barrier).
//  - never vmcnt(0) in the main loop; 1 barrier per BK=64 tile.
// Geometry: BM=256, BK=64, 512 thr (8 waves).  BN=128 (waves 2Mx4N) or
// BN=64 (4Mx2N) -> every grid >= 576 blocks (makespan quantization).
// =====================================================================
template <int NB>   // B-staging issues per thread (1: BN=64, 2: BN=128)
__device__ __forceinline__ void stage_t(const u16* pA, const u16* pB, size_t rs4,
                                        u16* bufA, u16* bufB, int w)
{
    u16* la = bufA + (w << 9);
    gld16(pA,            la);
    gld16(pA + rs4,      la + 4096);
    gld16(pA + 2 * rs4,  la + 8192);
    gld16(pA + 3 * rs4,  la + 12288);
    u16* lb = bufB + (w << 9);
    gld16(pB,            lb);
    if constexpr (NB == 2) gld16(pB + rs4, lb + 4096);
}

// MODE: 0 = exp+rowsum (logits), 1 = +bias[col] (qk), 2 = +bias[row] (V),
//       3 = *1/rowsum[row] (pv), 4 = fp32 row-major +bias[row] (out)
template <int MODE, int K, int BN, int WN>
__device__ __forceinline__ void gemm256_core(
    const u16* __restrict__ A, const u16* __restrict__ Bp,
    const float* __restrict__ aux, void* __restrict__ Cout,
    int N, int m0, int n0, float* __restrict__ rsG)
{
    constexpr int WM   = 8 / WN;
    constexpr int I    = 16 / WM;        // row fragments per wave
    constexpr int NB   = BN / 64;
    constexpr int ASZ  = 16384;          // 256x64 u16
    constexpr int BSZ  = BN * 64;
    constexpr int SBUF = ASZ + BSZ;
    constexpr int NT   = K / 64;

    __shared__ u16 lds[3 * SBUF];
    __shared__ float rowsumL[256];

    const int t  = threadIdx.x;
    const int w  = t >> 6, ln = t & 63;
    const int wr = w / WN, wc = w % WN;
    const int lrow = ln & 15, kq = ln >> 4;
    const int fo = (kq << 7) + (lrow << 3);

    if constexpr (MODE == 0) { if (t < 256) rowsumL[t] = 0.f; }

    // per-thread staging pointers: chunk idx = s*512 + t;
    // g = idx>>7 (+4 per issue), c = (t>>6)&1, l = t&63
    const int bpr = K >> 5;
    const size_t rs4 = (size_t)bpr << 11;   // 4 brick-rows in u16
    const u16* pA = A  + (((size_t)((m0 >> 4) + (t >> 7)) * bpr + ((t >> 6) & 1)) << 9)
                       + (size_t)((t & 63) << 3);
    const u16* pB = Bp + (((size_t)((n0 >> 4) + (t >> 7)) * bpr + ((t >> 6) & 1)) << 9)
                       + (size_t)((t & 63) << 3);

    u16* b0 = lds; u16* b1 = lds + SBUF; u16* b2 = lds + 2 * SBUF;

    stage_t<NB>(pA, pB, rs4, b0, b0 + ASZ, w); pA += 1024; pB += 1024;
    stage_t<NB>(pA, pB, rs4, b1, b1 + ASZ, w); pA += 1024; pB += 1024;

    u16 *cur = b0, *nxt = b1, *prv = b2;
    f32x4 acc[I][2] = {};

#pragma unroll 1
    for (int kt = 0; kt < NT; ++kt) {
        if (kt < NT - 1) {
            if constexpr (NB == 2) asm volatile("s_waitcnt vmcnt(6)" ::: "memory");
            else                   asm volatile("s_waitcnt vmcnt(5)" ::: "memory");
        } else {
            asm volatile("s_waitcnt vmcnt(0)" ::: "memory");
        }
        __builtin_amdgcn_s_barrier();
        asm volatile("" ::: "memory");
        if (kt + 2 < NT) {
            stage_t<NB>(pA, pB, rs4, prv, prv + ASZ, w);
            pA += 1024; pB += 1024;
        }
#pragma unroll
        for (int kk = 0; kk < 2; ++kk) {
            s16x8 a[I], b[2];
#pragma unroll
            for (int i = 0; i < I; ++i)
                a[i] = *(const s16x8*)(cur + (((wr * I + i) * 2 + kk) << 9) + fo);
#pragma unroll
            for (int j = 0; j < 2; ++j)
                b[j] = *(const s16x8*)(cur + ASZ + (((wc * 2 + j) * 2 + kk) << 9) + fo);
            __builtin_amdgcn_s_setprio(1);
#pragma unroll
            for (int i = 0; i < I; ++i)
#pragma unroll
                for (int j = 0; j < 2; ++j)
                    acc[i][j] = __builtin_amdgcn_mfma_f32_16x16x32_bf16(a[i], b[j], acc[i][j], 0, 0, 0);
            __builtin_amdgcn_s_setprio(0);
        }
        u16* tmp = cur; cur = nxt; nxt = prv; prv = tmp;
    }

    const int offl = ((lrow >> 3) << 7) + (lrow & 7) + (kq << 5);

    if constexpr (MODE == 0) {
        u16* E = (u16*)Cout;
#pragma unroll
        for (int i = 0; i < I; ++i) {
            u16* Erow = E + ((size_t)((m0 >> 4) + wr * I + i) * (N >> 5) + (n0 >> 5) + wc) * 512 + offl;
#pragma unroll
            for (int r = 0; r < 4; ++r) {
                float part = 0.f;
#pragma unroll
                for (int j = 0; j < 2; ++j) {
                    float e = __expf(acc[i][j][r] * SCALE);
                    part += e;
                    Erow[(j << 8) + r * 8] = f2bf(e);
                }
                part += __shfl_xor(part, 1);
                part += __shfl_xor(part, 2);
                part += __shfl_xor(part, 4);
                part += __shfl_xor(part, 8);
                if (lrow == 0) atomicAdd(&rowsumL[wr * (I * 16) + i * 16 + kq * 4 + r], part);
            }
        }
        __syncthreads();
        if (t < 256) atomicAdd(&rsG[m0 + t], rowsumL[t]);
    } else if constexpr (MODE == 4) {
        float* C = (float*)Cout;
#pragma unroll
        for (int i = 0; i < I; ++i) {
            const int row = m0 + wr * (I * 16) + i * 16 + kq * 4;
            const float4 b4 = *(const float4*)(aux + row);
            const float bv[4] = {b4.x, b4.y, b4.z, b4.w};
#pragma unroll
            for (int r = 0; r < 4; ++r)
#pragma unroll
                for (int j = 0; j < 2; ++j) {
                    const int col = n0 + wc * 32 + j * 16 + lrow;
                    C[(size_t)(row + r) * N + col] = acc[i][j][r] + bv[r];
                }
        }
    } else {
        u16* C = (u16*)Cout;
        float bcol[2];
        if constexpr (MODE == 1) {
#pragma unroll
            for (int j = 0; j < 2; ++j) bcol[j] = aux[n0 + wc * 32 + j * 16 + lrow];
        }
#pragma unroll
        for (int i = 0; i < I; ++i) {
            u16* Crow = C + ((size_t)((m0 >> 4) + wr * I + i) * (N >> 5) + (n0 >> 5) + wc) * 512 + offl;
            float rf[4] = {0.f, 0.f, 0.f, 0.f};
            if constexpr (MODE == 2) {
                const float4 b4 = *(const float4*)(aux + m0 + wr * (I * 16) + i * 16 + kq * 4);
                rf[0] = b4.x; rf[1] = b4.y; rf[2] = b4.z; rf[3] = b4.w;
            }
            if constexpr (MODE == 3) {
                const float4 s4 = *(const float4*)(aux + m0 + wr * (I * 16) + i * 16 + kq * 4);
                rf[0] = 1.f / s4.x; rf[1] = 1.f / s4.y; rf[2] = 1.f / s4.z; rf[3] = 1.f / s4.w;
            }
#pragma unroll
            for (int j = 0; j < 2; ++j) {
                u16* Cj = Crow + (j << 8);
#pragma unroll
                for (int r = 0; r < 4; ++r) {
                    float v = acc[i][j][r];
                    if constexpr (MODE == 1) v += bcol[j];
                    if constexpr (MODE == 2) v += rf[r];
                    if constexpr (MODE == 3) v *= rf[r];
                    Cj[r * 8] = f2bf(v);
                }
            }
        }
    }
}

// =====================================================================
// Kernel 0a: weight cast fp32 -> bf16, BRICK output.
// =====================================================================
#define WQKV_SZ (OCH * CIN)
#define WO_SZ   (OCH * OCH)
#define CH_QKV  (WQKV_SZ / 8)
#define CH_WO   (WO_SZ / 8)
#define CH_TOT  (3 * CH_QKV + CH_WO)

__global__ __launch_bounds__(256) void prep_w_kernel(
    const float* __restrict__ Wq, const float* __restrict__ Wk,
    const float* __restrict__ Wv, const float* __restrict__ Wo,
    u16* __restrict__ Wqb, u16* __restrict__ Wkb,
    u16* __restrict__ Wvb, u16* __restrict__ Wob)
{
    int lc = blockIdx.x * 256 + threadIdx.x;
    if (lc >= CH_TOT) return;
    const float* src; u16* dst; int Kc;
    if      (lc < CH_QKV)     { src = Wq; dst = Wqb; Kc = CIN; }
    else if (lc < 2 * CH_QKV) { src = Wk; dst = Wkb; Kc = CIN; lc -= CH_QKV; }
    else if (lc < 3 * CH_QKV) { src = Wv; dst = Wvb; Kc = CIN; lc -= 2 * CH_QKV; }
    else                      { src = Wo; dst = Wob; Kc = OCH; lc -= 3 * CH_QKV; }
    const int brick = lc >> 6, l = lc & 63;
    const int bpr = Kc >> 5;
    const int g = brick / bpr, c = brick % bpr;
    const int row = g * 16 + (l & 15);
    const int col = c * 32 + (l >> 4) * 8;
    const float* s = src + (size_t)row * Kc + col;
    float4 v0 = *(const float4*)s;
    float4 v1 = *(const float4*)(s + 4);
    u16x8 o;
    o[0] = f2bf(v0.x); o[1] = f2bf(v0.y); o[2] = f2bf(v0.z); o[3] = f2bf(v0.w);
    o[4] = f2bf(v1.x); o[5] = f2bf(v1.y); o[6] = f2bf(v1.z); o[7] = f2bf(v1.w);
    *(u16x8*)(dst + (size_t)lc * 8) = o;
}

// =====================================================================
// Kernel 0b: transpose x [B,C,N] fp32 -> xT [B,N,C] bf16 BRICK.
// =====================================================================
__global__ __launch_bounds__(256) void transpose_x_kernel(
    const float* __restrict__ x, u16* __restrict__ xT)
{
    const int n0 = blockIdx.x * 64;
    const int c0 = blockIdx.y * 64;
    const int b  = blockIdx.z;
    const float* X = x + (size_t)b * CIN * NTOK;

    __shared__ float Ts[64][66];

    const int t = threadIdx.x;
#pragma unroll
    for (int rep = 0; rep < 4; ++rep) {
        const int cr = (t >> 4) + rep * 16;
        const int n4 = (t & 15) * 4;
        float4 v = *(const float4*)(X + (size_t)(c0 + cr) * NTOK + n0 + n4);
        *(float2*)&Ts[cr][n4]     = make_float2(v.x, v.y);
        *(float2*)&Ts[cr][n4 + 2] = make_float2(v.z, v.w);
    }
    __syncthreads();

    u16* O = xT + (size_t)b * NTOK * CIN;
#pragma unroll
    for (int rep = 0; rep < 2; ++rep) {
        const int nr = (t >> 3) + rep * 32;
        const int c8 = (t & 7) * 8;
        u16 tmp[8];
#pragma unroll
        for (int j = 0; j < 8; ++j) tmp[j] = f2bf(Ts[c8 + j][nr]);
        *(u16x8*)(O + baddr(n0 + nr, c0 + c8, CIN)) = *(const u16x8*)tmp;
    }
}

// =====================================================================
// GEMM wrapper kernels (512 threads each)
// =====================================================================
__global__ __launch_bounds__(512) void qk256_kernel(
    const u16* __restrict__ xT,
    const u16* __restrict__ Wqb, const float* __restrict__ bq,
    const u16* __restrict__ Wkb, const float* __restrict__ bk,
    u16* __restrict__ Qt, u16* __restrict__ Kt)
{
    const int z = blockIdx.x & 15;
    const int b = z & 7, which = z >> 3;
    const int rem = blockIdx.x >> 4;        // 0..35
    const int n0 = (rem & 3) * 128;
    const int m0 = (rem >> 2) * 256;
    gemm256_core<1, CIN, 128, 4>(
        xT + (size_t)b * NTOK * CIN,
        which ? Wkb : Wqb, which ? bk : bq,
        (which ? Kt : Qt) + (size_t)b * NTOK * OCH,
        OCH, m0, n0, nullptr);
}

__global__ __launch_bounds__(512) void v256_kernel(
    const u16* __restrict__ Wvb, const u16* __restrict__ xT,
    const float* __restrict__ bv, u16* __restrict__ Vw)
{
    const int z = blockIdx.x & 7;
    const int rem = blockIdx.x >> 3;        // 0..71
    const int n0 = (rem % 36) * 64;
    const int m0 = (rem / 36) * 256;
    gemm256_core<2, CIN, 64, 2>(
        Wvb, xT + (size_t)z * NTOK * CIN, bv,
        Vw + (size_t)z * OCH * NTOK, NTOK, m0, n0, nullptr);
}

__global__ __launch_bounds__(512) void logits256_kernel(
    const u16* __restrict__ Qt, const u16* __restrict__ Kt,
    u16* __restrict__ Ew, float* __restrict__ rowsumG)
{
    const int z = blockIdx.x & 7;
    const int rem = blockIdx.x >> 3;        // 0..161
    const int n0 = (rem % 18) * 128;
    const int m0 = (rem / 18) * 256;
    gemm256_core<0, OCH, 128, 4>(
        Qt + (size_t)z * NTOK * OCH, Kt + (size_t)z * NTOK * OCH,
        nullptr, Ew + (size_t)z * NTOK * NTOK,
        NTOK, m0, n0, rowsumG + (size_t)z * NTOK);
}

__global__ __launch_bounds__(512) void pv256_kernel(
    const u16* __restrict__ Ew, const u16* __restrict__ Vw,
    const float* __restrict__ rowsumG, u16* __restrict__ AOt)
{
    const int z = blockIdx.x & 7;
    const int rem = blockIdx.x >> 3;        // 0..71
    const int n0 = (rem & 7) * 64;
    const int m0 = (rem >> 3) * 256;
    gemm256_core<3, NTOK, 64, 2>(
        Ew + (size_t)z * NTOK * NTOK, Vw + (size_t)z * OCH * NTOK,
        rowsumG + (size_t)z * NTOK, AOt + (size_t)z * NTOK * OCH,
        OCH, m0, n0, nullptr);
}

__global__ __launch_bounds__(512) void out256_kernel(
    const u16* __restrict__ Wob, const u16* __restrict__ AOt,
    const float* __restrict__ bo, float* __restrict__ out)
{
    const int z = blockIdx.x & 7;
    const int rem = blockIdx.x >> 3;        // 0..71
    const int n0 = (rem % 36) * 64;
    const int m0 = (rem / 36) * 256;
    gemm256_core<4, OCH, 64, 2>(
        Wob, AOt + (size_t)z * NTOK * OCH, bo,
        out + (size_t)z * OCH * NTOK, NTOK, m0, n0, nullptr);
}

// =====================================================================
extern "C" void kernel_launch(void* const* d_in, const int* in_sizes, int n_in,
                              void* d_out, int out_size, void* d_ws, size_t ws_size,
                              hipStream_t stream)
{
    const float* x  = (const float*)d_in[0];
    const float* Wq = (const float*)d_in[1];
    const float* bq = (const float*)d_in[2];
    const float* Wk = (const float*)d_in[3];
    const float* bk = (const float*)d_in[4];
    const float* Wv = (const float*)d_in[5];
    const float* bv = (const float*)d_in[6];
    const float* Wo = (const float*)d_in[7];
    const float* bo = (const float*)d_in[8];
    float* out = (float*)d_out;

    u16* ws = (u16*)d_ws;
    u16* Wqb = ws;
    u16* Wkb = Wqb + WQKV_SZ;
    u16* Wvb = Wkb + WQKV_SZ;
    u16* Wob = Wvb + WQKV_SZ;
    u16* xT  = Wob + WO_SZ;
    const size_t xtsz  = (size_t)B_ * NTOK * CIN;
    const size_t qkvsz = (size_t)B_ * NTOK * OCH;
    u16* Qt  = xT + xtsz;
    u16* Kt  = Qt + qkvsz;
    u16* Vw  = Kt + qkvsz;
    u16* Ew  = Vw + qkvsz;                          // B*N*N
    float* rowsumG = (float*)(Ew + (size_t)B_ * NTOK * NTOK);
    u16* AOt = Qt;                                  // alias: Qt dead after logits

    dim3 blk(256), blk512(512);

    prep_w_kernel<<<dim3((CH_TOT + 255) / 256), blk, 0, stream>>>(
        Wq, Wk, Wv, Wo, Wqb, Wkb, Wvb, Wob);
    transpose_x_kernel<<<dim3(NTOK / 64, CIN / 64, B_), blk, 0, stream>>>(x, xT);
    hipMemsetAsync(rowsumG, 0, (size_t)B_ * NTOK * sizeof(float), stream);

    // Q & K merged: (9 m-tiles x 4 n-tiles) x 16 (which*8+batch) = 576
    qk256_kernel<<<dim3(36 * 16), blk512, 0, stream>>>(
        xT, Wqb, bq, Wkb, bk, Qt, Kt);
    // V: (2 m-tiles x 36 n-tiles) x 8 = 576
    v256_kernel<<<dim3(72 * 8), blk512, 0, stream>>>(Wvb, xT, bv, Vw);

    // E = exp(scale * Qt.Kt^T), rowsum: (9 x 18) x 8 = 1296
    logits256_kernel<<<dim3(162 * 8), blk512, 0, stream>>>(Qt, Kt, Ew, rowsumG);

    // AOt = (E.V^T)/rowsum: (9 m-tiles x 8 n-tiles) x 8 = 576
    pv256_kernel<<<dim3(72 * 8), blk512, 0, stream>>>(Ew, Vw, rowsumG, AOt);

    // out = Wo.AOt + bo: (2 x 36) x 8 = 576
    out256_kernel<<<dim3(72 * 8), blk512, 0, stream>>>(Wob, AOt, bo, out);
}

// Round 5
// 295.714 us; speedup vs baseline: 1.1585x; 1.1585x over previous
//
#include <hip/hip_runtime.h>
#include <stdint.h>

// Problem constants (CorrelationModule): x[8,384,48,48], O=512, N=48*48=2304
#define B_    8
#define CIN   384
#define OCH   512
#define NTOK  2304
#define SCALE 0.044194173824159216f  // 1/sqrt(512)

typedef unsigned short u16;
typedef u16   u16x8 __attribute__((ext_vector_type(8)));
typedef short s16x8 __attribute__((ext_vector_type(8)));
typedef float f32x4 __attribute__((ext_vector_type(4)));

// ---------- bf16 helpers (bit-level, RNE) ----------
__device__ __forceinline__ u16 f2bf(float f) {
    union { uint32_t i; float f; } v; v.f = f;
    uint32_t r = v.i + 0x7fffu + ((v.i >> 16) & 1u);
    return (u16)(r >> 16);
}

// ---------- async global->LDS (width 16) ----------
typedef __attribute__((address_space(1))) const uint32_t glb_u32;
typedef __attribute__((address_space(3))) uint32_t lds_u32;

// =====================================================================
// BRICK FORMAT for all bf16 intermediates.
// brick (g, c) = rows g*16..+16, cols c*32..+32, 512 u16, chunk l (16 B)
// = (col8 = l>>4, row = l&15).  u16 offset of (row, col) inside brick:
//   ((col>>3)&3)*128 + (row&15)*8 + (col&7)
//
// R12 = exact R0 structure (the verified 304 µs schedule: stage-all;
// sync; mfma; sync; 128^2 tile; BK=32; 16 KB LDS) + R10's hoisted
// epilogue addressing only (pure VALU strength-reduction, HW-verified
// correct in R10).  R8/R9/R10/R11 structural variants all regressed:
// inter-block TLP does the latency hiding here; added LDS/barrier
// structure kills co-residency (m114 / m196 mechanism).
// =====================================================================
__device__ __forceinline__ size_t baddr(int row, int col, int Kc) {
    return ((size_t)(row >> 4) * (Kc >> 5) + (col >> 5)) * 512
         + (size_t)(((col >> 3) & 3) * 128 + (row & 15) * 8 + (col & 7));
}

// stage a 128x32 brick-format tile (rows row0..+128, cols k0..+32) into LDS
__device__ __forceinline__ void stage_blocked(const u16* __restrict__ base,
                                              int row0, int k0, int Kc,
                                              u16* __restrict__ dst, int t)
{
    const int lane = t & 63;
    const int w = t >> 6;
    const int bpr = Kc >> 5;
#pragma unroll
    for (int it = 0; it < 2; ++it) {
        const int ck = w * 2 + it;               // 0..7 (16-row groups)
        const u16* gp = base + ((size_t)((row0 >> 4) + ck) * bpr + (k0 >> 5)) * 512
                      + (size_t)lane * 8;
        u16* lp = dst + ck * 512;                // wave-uniform base
        __builtin_amdgcn_global_load_lds((glb_u32*)gp, (lds_u32*)lp, 16, 0, 0);
    }
}

// 2x2-wave 128x128 MFMA core (16 MFMA/wave per BK=32 step; proven R6/R7)
__device__ __forceinline__ void mfma_core(const u16* __restrict__ As,
                                          const u16* __restrict__ Bs,
                                          int wm16, int wn16, int lrow, int kq,
                                          f32x4 acc[4][4])
{
    s16x8 a[4], b[4];
#pragma unroll
    for (int i = 0; i < 4; ++i)
        a[i] = *(const s16x8*)(As + (((wm16 + i) * 64) + kq * 16 + lrow) * 8);
#pragma unroll
    for (int j = 0; j < 4; ++j)
        b[j] = *(const s16x8*)(Bs + (((wn16 + j) * 64) + kq * 16 + lrow) * 8);
#pragma unroll
    for (int i = 0; i < 4; ++i)
#pragma unroll
        for (int j = 0; j < 4; ++j)
            acc[i][j] = __builtin_amdgcn_mfma_f32_16x16x32_bf16(a[i], b[j], acc[i][j], 0, 0, 0);
}

// =====================================================================
// Kernel 0a: weight cast fp32 -> bf16, BRICK output.
// =====================================================================
#define WQKV_SZ (OCH * CIN)
#define WO_SZ   (OCH * OCH)
#define CH_QKV  (WQKV_SZ / 8)
#define CH_WO   (WO_SZ / 8)
#define CH_TOT  (3 * CH_QKV + CH_WO)

__global__ __launch_bounds__(256) void prep_w_kernel(
    const float* __restrict__ Wq, const float* __restrict__ Wk,
    const float* __restrict__ Wv, const float* __restrict__ Wo,
    u16* __restrict__ Wqb, u16* __restrict__ Wkb,
    u16* __restrict__ Wvb, u16* __restrict__ Wob)
{
    int lc = blockIdx.x * 256 + threadIdx.x;
    if (lc >= CH_TOT) return;
    const float* src; u16* dst; int Kc;
    if      (lc < CH_QKV)     { src = Wq; dst = Wqb; Kc = CIN; }
    else if (lc < 2 * CH_QKV) { src = Wk; dst = Wkb; Kc = CIN; lc -= CH_QKV; }
    else if (lc < 3 * CH_QKV) { src = Wv; dst = Wvb; Kc = CIN; lc -= 2 * CH_QKV; }
    else                      { src = Wo; dst = Wob; Kc = OCH; lc -= 3 * CH_QKV; }
    const int brick = lc >> 6, l = lc & 63;
    const int bpr = Kc >> 5;
    const int g = brick / bpr, c = brick % bpr;
    const int row = g * 16 + (l & 15);
    const int col = c * 32 + (l >> 4) * 8;
    const float* s = src + (size_t)row * Kc + col;
    float4 v0 = *(const float4*)s;
    float4 v1 = *(const float4*)(s + 4);
    u16x8 o;
    o[0] = f2bf(v0.x); o[1] = f2bf(v0.y); o[2] = f2bf(v0.z); o[3] = f2bf(v0.w);
    o[4] = f2bf(v1.x); o[5] = f2bf(v1.y); o[6] = f2bf(v1.z); o[7] = f2bf(v1.w);
    *(u16x8*)(dst + (size_t)lc * 8) = o;
}

// =====================================================================
// Kernel 0b: transpose x [B,C,N] fp32 -> xT [B,N,C] bf16 BRICK.
// =====================================================================
__global__ __launch_bounds__(256) void transpose_x_kernel(
    const float* __restrict__ x, u16* __restrict__ xT)
{
    const int n0 = blockIdx.x * 64;
    const int c0 = blockIdx.y * 64;
    const int b  = blockIdx.z;
    const float* X = x + (size_t)b * CIN * NTOK;

    __shared__ float Ts[64][66];

    const int t = threadIdx.x;
#pragma unroll
    for (int rep = 0; rep < 4; ++rep) {
        const int cr = (t >> 4) + rep * 16;
        const int n4 = (t & 15) * 4;
        float4 v = *(const float4*)(X + (size_t)(c0 + cr) * NTOK + n0 + n4);
        *(float2*)&Ts[cr][n4]     = make_float2(v.x, v.y);
        *(float2*)&Ts[cr][n4 + 2] = make_float2(v.z, v.w);
    }
    __syncthreads();

    u16* O = xT + (size_t)b * NTOK * CIN;
#pragma unroll
    for (int rep = 0; rep < 2; ++rep) {
        const int nr = (t >> 3) + rep * 32;
        const int c8 = (t & 7) * 8;
        u16 tmp[8];
#pragma unroll
        for (int j = 0; j < 8; ++j) tmp[j] = f2bf(Ts[c8 + j][nr]);
        *(u16x8*)(O + baddr(n0 + nr, c0 + c8, CIN)) = *(const u16x8*)tmp;
    }
}

// =====================================================================
// Merged Q+K projection (128x128, brick in/out): z = which*8 + batch.
// =====================================================================
__global__ __launch_bounds__(256) void qk_kernel(
    const u16* __restrict__ xT,
    const u16* __restrict__ Wqb, const float* __restrict__ bq,
    const u16* __restrict__ Wkb, const float* __restrict__ bk,
    u16* __restrict__ Qt, u16* __restrict__ Kt)
{
    const int zz  = blockIdx.x % 16;
    const int b   = zz & 7, which = zz >> 3;
    const int rem = blockIdx.x / 16;
    const int n0 = (rem % 4) * 128;
    const int m0 = (rem / 4) * 128;
    const u16* A  = xT + (size_t)b * NTOK * CIN;
    const u16* Bp = which ? Wkb : Wqb;
    const float* bias = which ? bk : bq;
    u16* C = (which ? Kt : Qt) + (size_t)b * NTOK * OCH;

    __shared__ u16 As[128 * 32];
    __shared__ u16 Bs[128 * 32];

    const int t = threadIdx.x;
    const int w = t >> 6, ln = t & 63;
    const int wm16 = (w & 1) * 4, wn16 = (w >> 1) * 4;
    const int lrow = ln & 15, kq = ln >> 4;

    f32x4 acc[4][4] = {};

    for (int k0 = 0; k0 < CIN; k0 += 32) {
        stage_blocked(A, m0, k0, CIN, As, t);
        stage_blocked(Bp, n0, k0, CIN, Bs, t);
        __syncthreads();
        mfma_core(As, Bs, wm16, wn16, lrow, kq, acc);
        __syncthreads();
    }

    // hoisted brick addressing (R10, HW-verified):
    // addr = base_i + ((wn16+j)>>1)*512 + (j&1)*256 + offl + r*8
    const int offl = ((lrow >> 3) << 7) + (lrow & 7) + (kq << 5);
    float bcol[4];
#pragma unroll
    for (int j = 0; j < 4; ++j)
        bcol[j] = bias[n0 + (wn16 + j) * 16 + lrow];
#pragma unroll
    for (int i = 0; i < 4; ++i) {
        u16* Crow = C + ((size_t)((m0 >> 4) + wm16 + i) * (OCH >> 5) + (n0 >> 5)) * 512 + offl;
#pragma unroll
        for (int j = 0; j < 4; ++j) {
            u16* Cj = Crow + ((wn16 + j) >> 1) * 512 + ((j & 1) << 8);
#pragma unroll
            for (int r = 0; r < 4; ++r)
                Cj[r * 8] = f2bf(acc[i][j][r] + bcol[j]);
        }
    }
}

// =====================================================================
// Generic MFMA GEMM (128x128, brick A/B): C[m][n] = sum_k A[m][k]*B[n][k]
// BIAS: 1 row bias.  OutT u16 -> brick C; float -> row-major C.
// =====================================================================
template <int BIAS, typename OutT>
__global__ __launch_bounds__(256) void gemm_kernel(
    const u16* __restrict__ Ag, const u16* __restrict__ Bg,
    const float* __restrict__ bias, OutT* __restrict__ Cg,
    int K, int N, long sA, long sB, long sC, int GX, int GZ)
{
    const int z   = blockIdx.x % GZ;
    const int rem = blockIdx.x / GZ;
    const int n0 = (rem % GX) * 128;
    const int m0 = (rem / GX) * 128;
    const u16* A  = Ag + (size_t)z * sA;
    const u16* Bp = Bg + (size_t)z * sB;
    OutT* C = Cg + (size_t)z * sC;

    __shared__ u16 As[128 * 32];
    __shared__ u16 Bs[128 * 32];

    const int t = threadIdx.x;
    const int w = t >> 6, ln = t & 63;
    const int wm16 = (w & 1) * 4, wn16 = (w >> 1) * 4;
    const int lrow = ln & 15, kq = ln >> 4;

    f32x4 acc[4][4] = {};

    for (int k0 = 0; k0 < K; k0 += 32) {
        stage_blocked(A, m0, k0, K, As, t);
        stage_blocked(Bp, n0, k0, K, Bs, t);
        __syncthreads();
        mfma_core(As, Bs, wm16, wn16, lrow, kq, acc);
        __syncthreads();
    }

    if constexpr (sizeof(OutT) == 2) {
        const int offl = ((lrow >> 3) << 7) + (lrow & 7) + (kq << 5);
#pragma unroll
        for (int i = 0; i < 4; ++i) {
            float4 b4 = make_float4(0.f, 0.f, 0.f, 0.f);
            if (BIAS == 1)
                b4 = *(const float4*)(bias + m0 + (wm16 + i) * 16 + kq * 4);
            u16* Crow = (u16*)C + ((size_t)((m0 >> 4) + wm16 + i) * (N >> 5) + (n0 >> 5)) * 512 + offl;
#pragma unroll
            for (int j = 0; j < 4; ++j) {
                u16* Cj = Crow + ((wn16 + j) >> 1) * 512 + ((j & 1) << 8);
                Cj[0]  = f2bf(acc[i][j][0] + b4.x);
                Cj[8]  = f2bf(acc[i][j][1] + b4.y);
                Cj[16] = f2bf(acc[i][j][2] + b4.z);
                Cj[24] = f2bf(acc[i][j][3] + b4.w);
            }
        }
    } else {
#pragma unroll
        for (int i = 0; i < 4; ++i) {
            const int row = m0 + (wm16 + i) * 16 + kq * 4;
#pragma unroll
            for (int r = 0; r < 4; ++r) {
                float badd = 0.f;
                if (BIAS == 1) badd = bias[row + r];
#pragma unroll
                for (int j = 0; j < 4; ++j) {
                    const int col = n0 + (wn16 + j) * 16 + lrow;
                    C[(size_t)(row + r) * N + col] = acc[i][j][r] + badd;
                }
            }
        }
    }
}

// =====================================================================
// Logits+exp kernel (128x128, brick): E[n][m] = exp(SCALE * Qt[n].Kt[m]);
// rowsumG[z][n] += partial row sums (fp32 device atomics).
// =====================================================================
__global__ __launch_bounds__(256) void logits_exp_kernel(
    const u16* __restrict__ Qt, const u16* __restrict__ Kt,
    u16* __restrict__ Ew, float* __restrict__ rowsumG)
{
    const int z   = blockIdx.x % B_;
    const int rem = blockIdx.x / B_;
    const int n0 = (rem % (NTOK / 128)) * 128;   // Kt token tiles, fast
    const int m0 = (rem / (NTOK / 128)) * 128;   // Qt token tiles
    const u16* A  = Qt + (size_t)z * NTOK * OCH;
    const u16* Bp = Kt + (size_t)z * NTOK * OCH;

    __shared__ u16 As[128 * 32];
    __shared__ u16 Bs[128 * 32];
    __shared__ float rowsumL[128];

    const int t = threadIdx.x;
    const int w = t >> 6, ln = t & 63;
    const int wm16 = (w & 1) * 4, wn16 = (w >> 1) * 4;
    const int lrow = ln & 15, kq = ln >> 4;

    if (t < 128) rowsumL[t] = 0.f;

    f32x4 acc[4][4] = {};

    for (int k0 = 0; k0 < OCH; k0 += 32) {
        stage_blocked(A, m0, k0, OCH, As, t);
        stage_blocked(Bp, n0, k0, OCH, Bs, t);
        __syncthreads();
        mfma_core(As, Bs, wm16, wn16, lrow, kq, acc);
        __syncthreads();
    }

    u16* E = Ew + (size_t)z * NTOK * NTOK;
    const int offl = ((lrow >> 3) << 7) + (lrow & 7) + (kq << 5);
#pragma unroll
    for (int i = 0; i < 4; ++i) {
        u16* Erow = E + ((size_t)((m0 >> 4) + wm16 + i) * (NTOK >> 5) + (n0 >> 5)) * 512 + offl;
#pragma unroll
        for (int r = 0; r < 4; ++r) {
            float part = 0.f;
#pragma unroll
            for (int j = 0; j < 4; ++j) {
                float e = __expf(acc[i][j][r] * SCALE);
                part += e;
                Erow[((wn16 + j) >> 1) * 512 + ((j & 1) << 8) + r * 8] = f2bf(e);
            }
            part += __shfl_xor(part, 1);
            part += __shfl_xor(part, 2);
            part += __shfl_xor(part, 4);
            part += __shfl_xor(part, 8);
            if (lrow == 0) atomicAdd(&rowsumL[(wm16 + i) * 16 + kq * 4 + r], part);
        }
    }
    __syncthreads();
    if (t < 128) atomicAdd(&rowsumG[(size_t)z * NTOK + m0 + t], rowsumL[t]);
}

// =====================================================================
// PV kernel (128x128, brick): AOt[n][o] = (sum_m E[n][m]*V[o][m]) / rowsum
// =====================================================================
__global__ __launch_bounds__(256) void pv_div_kernel(
    const u16* __restrict__ Ew, const u16* __restrict__ Vw,
    const float* __restrict__ rowsumG, u16* __restrict__ AOt)
{
    const int z   = blockIdx.x % B_;
    const int rem = blockIdx.x / B_;
    const int n0 = (rem % 4) * 128;              // o tiles, fast
    const int m0 = (rem / 4) * 128;              // token tiles
    const u16* A  = Ew + (size_t)z * NTOK * NTOK;
    const u16* Bp = Vw + (size_t)z * OCH * NTOK;

    __shared__ u16 As[128 * 32];
    __shared__ u16 Bs[128 * 32];

    const int t = threadIdx.x;
    const int w = t >> 6, ln = t & 63;
    const int wm16 = (w & 1) * 4, wn16 = (w >> 1) * 4;
    const int lrow = ln & 15, kq = ln >> 4;

    f32x4 acc[4][4] = {};

    for (int k0 = 0; k0 < NTOK; k0 += 32) {
        stage_blocked(A, m0, k0, NTOK, As, t);
        stage_blocked(Bp, n0, k0, NTOK, Bs, t);
        __syncthreads();
        mfma_core(As, Bs, wm16, wn16, lrow, kq, acc);
        __syncthreads();
    }

    u16* AO = AOt + (size_t)z * NTOK * OCH;
    const int offl = ((lrow >> 3) << 7) + (lrow & 7) + (kq << 5);
#pragma unroll
    for (int i = 0; i < 4; ++i) {
        const float4 rs4 = *(const float4*)(rowsumG + (size_t)z * NTOK + m0 + (wm16 + i) * 16 + kq * 4);
        const float inv0 = 1.0f / rs4.x, inv1 = 1.0f / rs4.y;
        const float inv2 = 1.0f / rs4.z, inv3 = 1.0f / rs4.w;
        u16* Crow = AO + ((size_t)((m0 >> 4) + wm16 + i) * (OCH >> 5) + (n0 >> 5)) * 512 + offl;
#pragma unroll
        for (int j = 0; j < 4; ++j) {
            u16* Cj = Crow + ((wn16 + j) >> 1) * 512 + ((j & 1) << 8);
            Cj[0]  = f2bf(acc[i][j][0] * inv0);
            Cj[8]  = f2bf(acc[i][j][1] * inv1);
            Cj[16] = f2bf(acc[i][j][2] * inv2);
            Cj[24] = f2bf(acc[i][j][3] * inv3);
        }
    }
}

// =====================================================================
extern "C" void kernel_launch(void* const* d_in, const int* in_sizes, int n_in,
                              void* d_out, int out_size, void* d_ws, size_t ws_size,
                              hipStream_t stream)
{
    const float* x  = (const float*)d_in[0];
    const float* Wq = (const float*)d_in[1];
    const float* bq = (const float*)d_in[2];
    const float* Wk = (const float*)d_in[3];
    const float* bk = (const float*)d_in[4];
    const float* Wv = (const float*)d_in[5];
    const float* bv = (const float*)d_in[6];
    const float* Wo = (const float*)d_in[7];
    const float* bo = (const float*)d_in[8];
    float* out = (float*)d_out;

    u16* ws = (u16*)d_ws;
    u16* Wqb = ws;
    u16* Wkb = Wqb + WQKV_SZ;
    u16* Wvb = Wkb + WQKV_SZ;
    u16* Wob = Wvb + WQKV_SZ;
    u16* xT  = Wob + WO_SZ;
    const size_t xtsz  = (size_t)B_ * NTOK * CIN;
    const size_t qkvsz = (size_t)B_ * NTOK * OCH;
    u16* Qt  = xT + xtsz;
    u16* Kt  = Qt + qkvsz;
    u16* Vw  = Kt + qkvsz;
    u16* Ew  = Vw + qkvsz;                          // B*N*N
    float* rowsumG = (float*)(Ew + (size_t)B_ * NTOK * NTOK);
    u16* AOt = Qt;                                  // alias: Qt dead after logits
    // total approx 157.5 MB

    dim3 blk(256);

    prep_w_kernel<<<dim3((CH_TOT + 255) / 256), blk, 0, stream>>>(
        Wq, Wk, Wv, Wo, Wqb, Wkb, Wvb, Wob);
    transpose_x_kernel<<<dim3(NTOK / 64, CIN / 64, B_), blk, 0, stream>>>(x, xT);
    hipMemsetAsync(rowsumG, 0, (size_t)B_ * NTOK * sizeof(float), stream);

    // Q & K merged: 4 o-tiles x 18 token-tiles x 16 (which*8+batch) = 1152
    qk_kernel<<<dim3(4 * 18 * 16), blk, 0, stream>>>(
        xT, Wqb, bq, Wkb, bk, Qt, Kt);
    // V[o][m] = Wv[o].xT[m] + bv[o]: 18 n-tiles (fast) x 4 m-tiles x 8 = 576
    gemm_kernel<1, u16><<<dim3(18 * 4 * B_), blk, 0, stream>>>(
        Wvb, xT, bv, Vw, CIN, NTOK, 0L, (long)NTOK * CIN, (long)OCH * NTOK, 18, B_);

    // E = exp(scale * Qt.Kt^T), rowsumG += row sums  (18x18x8 = 2592)
    logits_exp_kernel<<<dim3(18 * 18 * B_), blk, 0, stream>>>(Qt, Kt, Ew, rowsumG);

    // AOt = (E.V^T) / rowsum: 4 o-tiles (fast) x 18 token-tiles x 8 = 576
    pv_div_kernel<<<dim3(4 * 18 * B_), blk, 0, stream>>>(Ew, Vw, rowsumG, AOt);

    // out[p][n] = Wo[p].AOt[n] + bo[p]: 18 n-tiles (fast) x 4 p-tiles x 8 = 576
    gemm_kernel<1, float><<<dim3(18 * 4 * B_), blk, 0, stream>>>(
        Wob, AOt, bo, out, OCH, NTOK, 0L, (long)NTOK * OCH, (long)OCH * NTOK, 18, B_);
}

// Round 6
// 293.546 us; speedup vs baseline: 1.1671x; 1.0074x over previous
//
#include <hip/hip_runtime.h>
#include <stdint.h>

// Problem constants (CorrelationModule): x[8,384,48,48], O=512, N=48*48=2304
#define B_    8
#define CIN   384
#define OCH   512
#define NTOK  2304
#define SCALE 0.044194173824159216f  // 1/sqrt(512)

typedef unsigned short u16;
typedef u16   u16x8 __attribute__((ext_vector_type(8)));
typedef short s16x8 __attribute__((ext_vector_type(8)));
typedef float f32x4 __attribute__((ext_vector_type(4)));

// ---------- bf16 helpers (bit-level, RNE) ----------
__device__ __forceinline__ u16 f2bf(float f) {
    union { uint32_t i; float f; } v; v.f = f;
    uint32_t r = v.i + 0x7fffu + ((v.i >> 16) & 1u);
    return (u16)(r >> 16);
}

// ---------- async global->LDS (width 16) ----------
typedef __attribute__((address_space(1))) const uint32_t glb_u32;
typedef __attribute__((address_space(3))) uint32_t lds_u32;

// =====================================================================
// BRICK FORMAT for all bf16 intermediates.
// brick (g, c) = rows g*16..+16, cols c*32..+32, 512 u16, chunk l (16 B)
// = (col8 = l>>4, row = l&15).  u16 offset of (row, col) inside brick:
//   ((col>>3)&3)*128 + (row&15)*8 + (col&7)
//
// R13 = R12 (verified 295.7 µs: R0 2-barrier 128^2 K-loop + hoisted
// brick epilogues) + Q/K/V merged into ONE 1728-block kernel.
// Mechanism: V's standalone 576-block launch ran ~half-duration on a
// sub-filled machine serialized behind qk's tail; merging pays ramp/
// tail once and interleaves V blocks with Q/K for continuous fill.
// All GEMM-core code byte-identical to R12 (5 structural experiments
// regressed; this structure is at its shape ceiling per m102 curve).
// =====================================================================
__device__ __forceinline__ size_t baddr(int row, int col, int Kc) {
    return ((size_t)(row >> 4) * (Kc >> 5) + (col >> 5)) * 512
         + (size_t)(((col >> 3) & 3) * 128 + (row & 15) * 8 + (col & 7));
}

// stage a 128x32 brick-format tile (rows row0..+128, cols k0..+32) into LDS
__device__ __forceinline__ void stage_blocked(const u16* __restrict__ base,
                                              int row0, int k0, int Kc,
                                              u16* __restrict__ dst, int t)
{
    const int lane = t & 63;
    const int w = t >> 6;
    const int bpr = Kc >> 5;
#pragma unroll
    for (int it = 0; it < 2; ++it) {
        const int ck = w * 2 + it;               // 0..7 (16-row groups)
        const u16* gp = base + ((size_t)((row0 >> 4) + ck) * bpr + (k0 >> 5)) * 512
                      + (size_t)lane * 8;
        u16* lp = dst + ck * 512;                // wave-uniform base
        __builtin_amdgcn_global_load_lds((glb_u32*)gp, (lds_u32*)lp, 16, 0, 0);
    }
}

// 2x2-wave 128x128 MFMA core (16 MFMA/wave per BK=32 step; proven R6/R7)
__device__ __forceinline__ void mfma_core(const u16* __restrict__ As,
                                          const u16* __restrict__ Bs,
                                          int wm16, int wn16, int lrow, int kq,
                                          f32x4 acc[4][4])
{
    s16x8 a[4], b[4];
#pragma unroll
    for (int i = 0; i < 4; ++i)
        a[i] = *(const s16x8*)(As + (((wm16 + i) * 64) + kq * 16 + lrow) * 8);
#pragma unroll
    for (int j = 0; j < 4; ++j)
        b[j] = *(const s16x8*)(Bs + (((wn16 + j) * 64) + kq * 16 + lrow) * 8);
#pragma unroll
    for (int i = 0; i < 4; ++i)
#pragma unroll
        for (int j = 0; j < 4; ++j)
            acc[i][j] = __builtin_amdgcn_mfma_f32_16x16x32_bf16(a[i], b[j], acc[i][j], 0, 0, 0);
}

// =====================================================================
// Kernel 0a: weight cast fp32 -> bf16, BRICK output.
// =====================================================================
#define WQKV_SZ (OCH * CIN)
#define WO_SZ   (OCH * OCH)
#define CH_QKV  (WQKV_SZ / 8)
#define CH_WO   (WO_SZ / 8)
#define CH_TOT  (3 * CH_QKV + CH_WO)

__global__ __launch_bounds__(256) void prep_w_kernel(
    const float* __restrict__ Wq, const float* __restrict__ Wk,
    const float* __restrict__ Wv, const float* __restrict__ Wo,
    u16* __restrict__ Wqb, u16* __restrict__ Wkb,
    u16* __restrict__ Wvb, u16* __restrict__ Wob)
{
    int lc = blockIdx.x * 256 + threadIdx.x;
    if (lc >= CH_TOT) return;
    const float* src; u16* dst; int Kc;
    if      (lc < CH_QKV)     { src = Wq; dst = Wqb; Kc = CIN; }
    else if (lc < 2 * CH_QKV) { src = Wk; dst = Wkb; Kc = CIN; lc -= CH_QKV; }
    else if (lc < 3 * CH_QKV) { src = Wv; dst = Wvb; Kc = CIN; lc -= 2 * CH_QKV; }
    else                      { src = Wo; dst = Wob; Kc = OCH; lc -= 3 * CH_QKV; }
    const int brick = lc >> 6, l = lc & 63;
    const int bpr = Kc >> 5;
    const int g = brick / bpr, c = brick % bpr;
    const int row = g * 16 + (l & 15);
    const int col = c * 32 + (l >> 4) * 8;
    const float* s = src + (size_t)row * Kc + col;
    float4 v0 = *(const float4*)s;
    float4 v1 = *(const float4*)(s + 4);
    u16x8 o;
    o[0] = f2bf(v0.x); o[1] = f2bf(v0.y); o[2] = f2bf(v0.z); o[3] = f2bf(v0.w);
    o[4] = f2bf(v1.x); o[5] = f2bf(v1.y); o[6] = f2bf(v1.z); o[7] = f2bf(v1.w);
    *(u16x8*)(dst + (size_t)lc * 8) = o;
}

// =====================================================================
// Kernel 0b: transpose x [B,C,N] fp32 -> xT [B,N,C] bf16 BRICK.
// =====================================================================
__global__ __launch_bounds__(256) void transpose_x_kernel(
    const float* __restrict__ x, u16* __restrict__ xT)
{
    const int n0 = blockIdx.x * 64;
    const int c0 = blockIdx.y * 64;
    const int b  = blockIdx.z;
    const float* X = x + (size_t)b * CIN * NTOK;

    __shared__ float Ts[64][66];

    const int t = threadIdx.x;
#pragma unroll
    for (int rep = 0; rep < 4; ++rep) {
        const int cr = (t >> 4) + rep * 16;
        const int n4 = (t & 15) * 4;
        float4 v = *(const float4*)(X + (size_t)(c0 + cr) * NTOK + n0 + n4);
        *(float2*)&Ts[cr][n4]     = make_float2(v.x, v.y);
        *(float2*)&Ts[cr][n4 + 2] = make_float2(v.z, v.w);
    }
    __syncthreads();

    u16* O = xT + (size_t)b * NTOK * CIN;
#pragma unroll
    for (int rep = 0; rep < 2; ++rep) {
        const int nr = (t >> 3) + rep * 32;
        const int c8 = (t & 7) * 8;
        u16 tmp[8];
#pragma unroll
        for (int j = 0; j < 8; ++j) tmp[j] = f2bf(Ts[c8 + j][nr]);
        *(u16x8*)(O + baddr(n0 + nr, c0 + c8, CIN)) = *(const u16x8*)tmp;
    }
}

// =====================================================================
// Merged Q+K+V projection kernel (128x128, brick in/out), K=CIN.
// sel = bid % 24: b = sel&7 (== bid%8 == XCD, since 24%8==0),
// which = sel>>3 (0=Q, 1=K, 2=V).  rem = bid/24 picks the tile:
//  which<2: C[tok][o]  = xT.Wq/k^T + b (col-bias), 18 m x 4 n
//  which=2: C[o][tok]  = Wv.xT^T  + b (row-bias), 4 m x 18 n
// =====================================================================
__global__ __launch_bounds__(256) void qkv_kernel(
    const u16* __restrict__ xT,
    const u16* __restrict__ Wqb, const float* __restrict__ bq,
    const u16* __restrict__ Wkb, const float* __restrict__ bk,
    const u16* __restrict__ Wvb, const float* __restrict__ bv,
    u16* __restrict__ Qt, u16* __restrict__ Kt, u16* __restrict__ Vw)
{
    const int sel = blockIdx.x % 24;
    const int b = sel & 7, which = sel >> 3;
    const int rem = blockIdx.x / 24;
    const u16* xTb = xT + (size_t)b * NTOK * CIN;

    int m0, n0, N;
    const u16 *A, *Bp;
    const float* bias;
    u16* C;
    if (which < 2) {
        n0 = (rem & 3) * 128; m0 = (rem >> 2) * 128;
        A = xTb; Bp = which ? Wkb : Wqb; bias = which ? bk : bq;
        C = (which ? Kt : Qt) + (size_t)b * NTOK * OCH; N = OCH;
    } else {
        n0 = (rem % 18) * 128; m0 = (rem / 18) * 128;
        A = Wvb; Bp = xTb; bias = bv;
        C = Vw + (size_t)b * OCH * NTOK; N = NTOK;
    }

    __shared__ u16 As[128 * 32];
    __shared__ u16 Bs[128 * 32];

    const int t = threadIdx.x;
    const int w = t >> 6, ln = t & 63;
    const int wm16 = (w & 1) * 4, wn16 = (w >> 1) * 4;
    const int lrow = ln & 15, kq = ln >> 4;

    f32x4 acc[4][4] = {};

    for (int k0 = 0; k0 < CIN; k0 += 32) {
        stage_blocked(A, m0, k0, CIN, As, t);
        stage_blocked(Bp, n0, k0, CIN, Bs, t);
        __syncthreads();
        mfma_core(As, Bs, wm16, wn16, lrow, kq, acc);
        __syncthreads();
    }

    const int offl = ((lrow >> 3) << 7) + (lrow & 7) + (kq << 5);
    if (which < 2) {
        // col-bias epilogue (hoisted brick addressing, R10/R12-verified)
        float bcol[4];
#pragma unroll
        for (int j = 0; j < 4; ++j)
            bcol[j] = bias[n0 + (wn16 + j) * 16 + lrow];
#pragma unroll
        for (int i = 0; i < 4; ++i) {
            u16* Crow = C + ((size_t)((m0 >> 4) + wm16 + i) * (N >> 5) + (n0 >> 5)) * 512 + offl;
#pragma unroll
            for (int j = 0; j < 4; ++j) {
                u16* Cj = Crow + ((wn16 + j) >> 1) * 512 + ((j & 1) << 8);
#pragma unroll
                for (int r = 0; r < 4; ++r)
                    Cj[r * 8] = f2bf(acc[i][j][r] + bcol[j]);
            }
        }
    } else {
        // row-bias epilogue
#pragma unroll
        for (int i = 0; i < 4; ++i) {
            const float4 b4 = *(const float4*)(bias + m0 + (wm16 + i) * 16 + kq * 4);
            u16* Crow = C + ((size_t)((m0 >> 4) + wm16 + i) * (N >> 5) + (n0 >> 5)) * 512 + offl;
#pragma unroll
            for (int j = 0; j < 4; ++j) {
                u16* Cj = Crow + ((wn16 + j) >> 1) * 512 + ((j & 1) << 8);
                Cj[0]  = f2bf(acc[i][j][0] + b4.x);
                Cj[8]  = f2bf(acc[i][j][1] + b4.y);
                Cj[16] = f2bf(acc[i][j][2] + b4.z);
                Cj[24] = f2bf(acc[i][j][3] + b4.w);
            }
        }
    }
}

// =====================================================================
// Generic MFMA GEMM (128x128, brick A/B): C[m][n] = sum_k A[m][k]*B[n][k]
// BIAS: 1 row bias.  OutT u16 -> brick C; float -> row-major C.
// (Used only for the fp32-out Wo projection now.)
// =====================================================================
template <int BIAS, typename OutT>
__global__ __launch_bounds__(256) void gemm_kernel(
    const u16* __restrict__ Ag, const u16* __restrict__ Bg,
    const float* __restrict__ bias, OutT* __restrict__ Cg,
    int K, int N, long sA, long sB, long sC, int GX, int GZ)
{
    const int z   = blockIdx.x % GZ;
    const int rem = blockIdx.x / GZ;
    const int n0 = (rem % GX) * 128;
    const int m0 = (rem / GX) * 128;
    const u16* A  = Ag + (size_t)z * sA;
    const u16* Bp = Bg + (size_t)z * sB;
    OutT* C = Cg + (size_t)z * sC;

    __shared__ u16 As[128 * 32];
    __shared__ u16 Bs[128 * 32];

    const int t = threadIdx.x;
    const int w = t >> 6, ln = t & 63;
    const int wm16 = (w & 1) * 4, wn16 = (w >> 1) * 4;
    const int lrow = ln & 15, kq = ln >> 4;

    f32x4 acc[4][4] = {};

    for (int k0 = 0; k0 < K; k0 += 32) {
        stage_blocked(A, m0, k0, K, As, t);
        stage_blocked(Bp, n0, k0, K, Bs, t);
        __syncthreads();
        mfma_core(As, Bs, wm16, wn16, lrow, kq, acc);
        __syncthreads();
    }

    if constexpr (sizeof(OutT) == 2) {
        const int offl = ((lrow >> 3) << 7) + (lrow & 7) + (kq << 5);
#pragma unroll
        for (int i = 0; i < 4; ++i) {
            float4 b4 = make_float4(0.f, 0.f, 0.f, 0.f);
            if (BIAS == 1)
                b4 = *(const float4*)(bias + m0 + (wm16 + i) * 16 + kq * 4);
            u16* Crow = (u16*)C + ((size_t)((m0 >> 4) + wm16 + i) * (N >> 5) + (n0 >> 5)) * 512 + offl;
#pragma unroll
            for (int j = 0; j < 4; ++j) {
                u16* Cj = Crow + ((wn16 + j) >> 1) * 512 + ((j & 1) << 8);
                Cj[0]  = f2bf(acc[i][j][0] + b4.x);
                Cj[8]  = f2bf(acc[i][j][1] + b4.y);
                Cj[16] = f2bf(acc[i][j][2] + b4.z);
                Cj[24] = f2bf(acc[i][j][3] + b4.w);
            }
        }
    } else {
#pragma unroll
        for (int i = 0; i < 4; ++i) {
            const int row = m0 + (wm16 + i) * 16 + kq * 4;
#pragma unroll
            for (int r = 0; r < 4; ++r) {
                float badd = 0.f;
                if (BIAS == 1) badd = bias[row + r];
#pragma unroll
                for (int j = 0; j < 4; ++j) {
                    const int col = n0 + (wn16 + j) * 16 + lrow;
                    C[(size_t)(row + r) * N + col] = acc[i][j][r] + badd;
                }
            }
        }
    }
}

// =====================================================================
// Logits+exp kernel (128x128, brick): E[n][m] = exp(SCALE * Qt[n].Kt[m]);
// rowsumG[z][n] += partial row sums (fp32 device atomics).
// =====================================================================
__global__ __launch_bounds__(256) void logits_exp_kernel(
    const u16* __restrict__ Qt, const u16* __restrict__ Kt,
    u16* __restrict__ Ew, float* __restrict__ rowsumG)
{
    const int z   = blockIdx.x % B_;
    const int rem = blockIdx.x / B_;
    const int n0 = (rem % (NTOK / 128)) * 128;   // Kt token tiles, fast
    const int m0 = (rem / (NTOK / 128)) * 128;   // Qt token tiles
    const u16* A  = Qt + (size_t)z * NTOK * OCH;
    const u16* Bp = Kt + (size_t)z * NTOK * OCH;

    __shared__ u16 As[128 * 32];
    __shared__ u16 Bs[128 * 32];
    __shared__ float rowsumL[128];

    const int t = threadIdx.x;
    const int w = t >> 6, ln = t & 63;
    const int wm16 = (w & 1) * 4, wn16 = (w >> 1) * 4;
    const int lrow = ln & 15, kq = ln >> 4;

    if (t < 128) rowsumL[t] = 0.f;

    f32x4 acc[4][4] = {};

    for (int k0 = 0; k0 < OCH; k0 += 32) {
        stage_blocked(A, m0, k0, OCH, As, t);
        stage_blocked(Bp, n0, k0, OCH, Bs, t);
        __syncthreads();
        mfma_core(As, Bs, wm16, wn16, lrow, kq, acc);
        __syncthreads();
    }

    u16* E = Ew + (size_t)z * NTOK * NTOK;
    const int offl = ((lrow >> 3) << 7) + (lrow & 7) + (kq << 5);
#pragma unroll
    for (int i = 0; i < 4; ++i) {
        u16* Erow = E + ((size_t)((m0 >> 4) + wm16 + i) * (NTOK >> 5) + (n0 >> 5)) * 512 + offl;
#pragma unroll
        for (int r = 0; r < 4; ++r) {
            float part = 0.f;
#pragma unroll
            for (int j = 0; j < 4; ++j) {
                float e = __expf(acc[i][j][r] * SCALE);
                part += e;
                Erow[((wn16 + j) >> 1) * 512 + ((j & 1) << 8) + r * 8] = f2bf(e);
            }
            part += __shfl_xor(part, 1);
            part += __shfl_xor(part, 2);
            part += __shfl_xor(part, 4);
            part += __shfl_xor(part, 8);
            if (lrow == 0) atomicAdd(&rowsumL[(wm16 + i) * 16 + kq * 4 + r], part);
        }
    }
    __syncthreads();
    if (t < 128) atomicAdd(&rowsumG[(size_t)z * NTOK + m0 + t], rowsumL[t]);
}

// =====================================================================
// PV kernel (128x128, brick): AOt[n][o] = (sum_m E[n][m]*V[o][m]) / rowsum
// =====================================================================
__global__ __launch_bounds__(256) void pv_div_kernel(
    const u16* __restrict__ Ew, const u16* __restrict__ Vw,
    const float* __restrict__ rowsumG, u16* __restrict__ AOt)
{
    const int z   = blockIdx.x % B_;
    const int rem = blockIdx.x / B_;
    const int n0 = (rem % 4) * 128;              // o tiles, fast
    const int m0 = (rem / 4) * 128;              // token tiles
    const u16* A  = Ew + (size_t)z * NTOK * NTOK;
    const u16* Bp = Vw + (size_t)z * OCH * NTOK;

    __shared__ u16 As[128 * 32];
    __shared__ u16 Bs[128 * 32];

    const int t = threadIdx.x;
    const int w = t >> 6, ln = t & 63;
    const int wm16 = (w & 1) * 4, wn16 = (w >> 1) * 4;
    const int lrow = ln & 15, kq = ln >> 4;

    f32x4 acc[4][4] = {};

    for (int k0 = 0; k0 < NTOK; k0 += 32) {
        stage_blocked(A, m0, k0, NTOK, As, t);
        stage_blocked(Bp, n0, k0, NTOK, Bs, t);
        __syncthreads();
        mfma_core(As, Bs, wm16, wn16, lrow, kq, acc);
        __syncthreads();
    }

    u16* AO = AOt + (size_t)z * NTOK * OCH;
    const int offl = ((lrow >> 3) << 7) + (lrow & 7) + (kq << 5);
#pragma unroll
    for (int i = 0; i < 4; ++i) {
        const float4 rs4 = *(const float4*)(rowsumG + (size_t)z * NTOK + m0 + (wm16 + i) * 16 + kq * 4);
        const float inv0 = 1.0f / rs4.x, inv1 = 1.0f / rs4.y;
        const float inv2 = 1.0f / rs4.z, inv3 = 1.0f / rs4.w;
        u16* Crow = AO + ((size_t)((m0 >> 4) + wm16 + i) * (OCH >> 5) + (n0 >> 5)) * 512 + offl;
#pragma unroll
        for (int j = 0; j < 4; ++j) {
            u16* Cj = Crow + ((wn16 + j) >> 1) * 512 + ((j & 1) << 8);
            Cj[0]  = f2bf(acc[i][j][0] * inv0);
            Cj[8]  = f2bf(acc[i][j][1] * inv1);
            Cj[16] = f2bf(acc[i][j][2] * inv2);
            Cj[24] = f2bf(acc[i][j][3] * inv3);
        }
    }
}

// =====================================================================
extern "C" void kernel_launch(void* const* d_in, const int* in_sizes, int n_in,
                              void* d_out, int out_size, void* d_ws, size_t ws_size,
                              hipStream_t stream)
{
    const float* x  = (const float*)d_in[0];
    const float* Wq = (const float*)d_in[1];
    const float* bq = (const float*)d_in[2];
    const float* Wk = (const float*)d_in[3];
    const float* bk = (const float*)d_in[4];
    const float* Wv = (const float*)d_in[5];
    const float* bv = (const float*)d_in[6];
    const float* Wo = (const float*)d_in[7];
    const float* bo = (const float*)d_in[8];
    float* out = (float*)d_out;

    u16* ws = (u16*)d_ws;
    u16* Wqb = ws;
    u16* Wkb = Wqb + WQKV_SZ;
    u16* Wvb = Wkb + WQKV_SZ;
    u16* Wob = Wvb + WQKV_SZ;
    u16* xT  = Wob + WO_SZ;
    const size_t xtsz  = (size_t)B_ * NTOK * CIN;
    const size_t qkvsz = (size_t)B_ * NTOK * OCH;
    u16* Qt  = xT + xtsz;
    u16* Kt  = Qt + qkvsz;
    u16* Vw  = Kt + qkvsz;
    u16* Ew  = Vw + qkvsz;                          // B*N*N
    float* rowsumG = (float*)(Ew + (size_t)B_ * NTOK * NTOK);
    u16* AOt = Qt;                                  // alias: Qt dead after logits
    // total approx 157.5 MB

    dim3 blk(256);

    prep_w_kernel<<<dim3((CH_TOT + 255) / 256), blk, 0, stream>>>(
        Wq, Wk, Wv, Wo, Wqb, Wkb, Wvb, Wob);
    transpose_x_kernel<<<dim3(NTOK / 64, CIN / 64, B_), blk, 0, stream>>>(x, xT);
    hipMemsetAsync(rowsumG, 0, (size_t)B_ * NTOK * sizeof(float), stream);

    // Q + K + V merged: 72 tiles x 24 (which*8+batch) = 1728
    qkv_kernel<<<dim3(72 * 24), blk, 0, stream>>>(
        xT, Wqb, bq, Wkb, bk, Wvb, bv, Qt, Kt, Vw);

    // E = exp(scale * Qt.Kt^T), rowsumG += row sums  (18x18x8 = 2592)
    logits_exp_kernel<<<dim3(18 * 18 * B_), blk, 0, stream>>>(Qt, Kt, Ew, rowsumG);

    // AOt = (E.V^T) / rowsum: 4 o-tiles (fast) x 18 token-tiles x 8 = 576
    pv_div_kernel<<<dim3(4 * 18 * B_), blk, 0, stream>>>(Ew, Vw, rowsumG, AOt);

    // out[p][n] = Wo[p].AOt[n] + bo[p]: 18 n-tiles (fast) x 4 p-tiles x 8 = 576
    gemm_kernel<1, float><<<dim3(18 * 4 * B_), blk, 0, stream>>>(
        Wob, AOt, bo, out, OCH, NTOK, 0L, (long)NTOK * OCH, (long)OCH * NTOK, 18, B_);
}